// Round 4
// baseline (1197.575 us; speedup 1.0000x reference)
//
#include <hip/hip_runtime.h>
#include <stdint.h>

typedef __attribute__((ext_vector_type(8))) short short8;
typedef __attribute__((ext_vector_type(4))) float f32x4;
typedef __attribute__((ext_vector_type(4))) unsigned short us4;
typedef unsigned short ushort_t;

__device__ __forceinline__ unsigned short f2bf(float f) {
  union { float f; unsigned int i; } v; v.f = f;
  return (unsigned short)((v.i + 0x7FFFu + ((v.i >> 16) & 1u)) >> 16);
}
__device__ __forceinline__ float hswish(float x) {
  float t = fminf(fmaxf(x + 3.f, 0.f), 6.f);
  return x * t * (1.f / 6.f);
}
__device__ __forceinline__ short8 ldcvt8(const float* __restrict__ p) {
  float4 v0 = *(const float4*)p;
  float4 v1 = *(const float4*)(p + 4);
  short8 r;
  r[0] = (short)f2bf(v0.x); r[1] = (short)f2bf(v0.y);
  r[2] = (short)f2bf(v0.z); r[3] = (short)f2bf(v0.w);
  r[4] = (short)f2bf(v1.x); r[5] = (short)f2bf(v1.y);
  r[6] = (short)f2bf(v1.z); r[7] = (short)f2bf(v1.w);
  return r;
}

// ws byte offsets
#define WS16_OFF      0ULL         // bf16 weights: 425984 B
#define M1T_OFF       425984ULL    // fp32 4096x64: 1048576 B
#define LGT0_OFF      1474560ULL   // fp32 128x128
#define LBT0_OFF      1540096ULL
#define LGT1_OFF      1605632ULL   // fp32 128x64
#define LBT1_OFF      1638400ULL
#define LGT2_OFF      1671168ULL   // fp32 128x32
#define LBT2_OFF      1687552ULL
#define H_OFF         1703936ULL   // fp32 4096x224
#define STATS_OFF     5373952ULL   // 64 floats (32 slots x {sum,sumsq})
#define A_OFF         5374208ULL   // fp32 64x224
#define CVEC_OFF      5431552ULL   // 64 floats
#define XBF_OFF       8388608ULL   // bf16 4096x128x128: 134217728 B
#define WS_NEED       142606336ULL

// ---------------------------------------------------------------------------
// Prep: weights->bf16 (cwLT m=j*128+i; L1/L2 block-diag tril 128x128),
//       M1 transpose (fp32), lg/lb transpose (fp32)
// ---------------------------------------------------------------------------
__global__ void prep_kernel(const float* __restrict__ cw0, const float* __restrict__ cw1,
                            const float* __restrict__ cw2,
                            const float* __restrict__ L1_0, const float* __restrict__ L2_0,
                            const float* __restrict__ L1_1, const float* __restrict__ L2_1,
                            const float* __restrict__ L1_2, const float* __restrict__ L2_2,
                            const float* __restrict__ M1,
                            const float* __restrict__ lg0, const float* __restrict__ lb0,
                            const float* __restrict__ lg1, const float* __restrict__ lb1,
                            const float* __restrict__ lg2, const float* __restrict__ lb2,
                            char* __restrict__ ws) {
  unsigned short* ws16 = (unsigned short*)(ws + WS16_OFF);
  float* m1t  = (float*)(ws + M1T_OFF);
  float* lgT0 = (float*)(ws + LGT0_OFF); float* lbT0 = (float*)(ws + LBT0_OFF);
  float* lgT1 = (float*)(ws + LGT1_OFF); float* lbT1 = (float*)(ws + LBT1_OFF);
  float* lgT2 = (float*)(ws + LGT2_OFF); float* lbT2 = (float*)(ws + LBT2_OFF);
  int idx = blockIdx.x * 256 + threadIdx.x;
  if (idx < 16384) {
    ws16[idx] = f2bf(cw0[idx]);
  } else if (idx < 49152) {
    int t = idx - 16384; int o = t >> 8, m = t & 255, j = m >> 7, i = m & 127;
    ws16[idx] = f2bf(cw1[(o * 128 + i) * 2 + j]);
  } else if (idx < 114688) {
    int t = idx - 49152; int o = t >> 9, m = t & 511, j = m >> 7, i = m & 127;
    ws16[idx] = f2bf(cw2[(o * 128 + i) * 4 + j]);
  } else if (idx < 212992) {
    int u = idx - 114688; int which = u >> 14; int e = u & 16383;
    int t = e >> 7, s = e & 127;
    float val = 0.f;
    if (which == 0)      { if (s <= t) val = L1_0[t * 128 + s]; }
    else if (which == 1) { if (s <= t) val = L2_0[t * 128 + s]; }
    else if (which == 2) { if ((s >> 6) == (t >> 6) && (s & 63) <= (t & 63)) val = L1_1[(t & 63) * 64 + (s & 63)]; }
    else if (which == 3) { if ((s >> 6) == (t >> 6) && (s & 63) <= (t & 63)) val = L2_1[(t & 63) * 64 + (s & 63)]; }
    else if (which == 4) { if ((s >> 5) == (t >> 5) && (s & 31) <= (t & 31)) val = L1_2[(t & 31) * 32 + (s & 31)]; }
    else                 { if ((s >> 5) == (t >> 5) && (s & 31) <= (t & 31)) val = L2_2[(t & 31) * 32 + (s & 31)]; }
    ws16[idx] = f2bf(val);
  } else if (idx < 475136) {
    int e = idx - 212992; int n = e >> 6, r = e & 63;
    m1t[e] = M1[r * 4096 + n];
  } else if (idx < 491520) {
    int e = idx - 475136; int f = e >> 7, t = e & 127; lgT0[e] = lg0[t * 128 + f];
  } else if (idx < 507904) {
    int e = idx - 491520; int f = e >> 7, t = e & 127; lbT0[e] = lb0[t * 128 + f];
  } else if (idx < 516096) {
    int e = idx - 507904; int f = e >> 6, t = e & 63;  lgT1[e] = lg1[t * 128 + f];
  } else if (idx < 524288) {
    int e = idx - 516096; int f = e >> 6, t = e & 63;  lbT1[e] = lb1[t * 128 + f];
  } else if (idx < 528384) {
    int e = idx - 524288; int f = e >> 5, t = e & 31;  lgT2[e] = lg2[t * 128 + f];
  } else if (idx < 532480) {
    int e = idx - 528384; int f = e >> 5, t = e & 31;  lbT2[e] = lb2[t * 128 + f];
  }
}

// x (fp32) -> xbf (bf16)
__global__ void xcvt_kernel(const float* __restrict__ x, unsigned short* __restrict__ xbf) {
  const float4* x4 = (const float4*)x;
  us4* o4 = (us4*)xbf;
#pragma unroll
  for (int j = 0; j < 4; ++j) {
    int idx = blockIdx.x * 1024 + j * 256 + threadIdx.x;
    float4 v = x4[idx];
    us4 p; p[0] = f2bf(v.x); p[1] = f2bf(v.y); p[2] = f2bf(v.z); p[3] = f2bf(v.w);
    o4[idx] = p;
  }
}

// ---------------------------------------------------------------------------
// Stage 1: wave-private columns. Wave owns 2 o-tiles (32 f) x all 8 t-tiles.
// 2 barriers per block. S in {0,1,2}; block covers 128 rows = 2^S samples.
// ---------------------------------------------------------------------------
template <int S, bool XBF>
__launch_bounds__(256, 3)
__global__ void s1_wp(const float* __restrict__ xf, const unsigned short* __restrict__ xb,
                      const float* __restrict__ cb,
                      const float* __restrict__ lgT, const float* __restrict__ lbT,
                      const float* __restrict__ fc_w, const float* __restrict__ fc_b,
                      const unsigned short* __restrict__ cwLT,
                      const unsigned short* __restrict__ L1blk,
                      const unsigned short* __restrict__ L2blk,
                      float* __restrict__ h_out, float* __restrict__ stats) {
  constexpr int K = 128 << S;
  constexpr int TK = 128 >> S;
  constexpr int L2TK = 7 - S;
  constexpr int GSH = 3 - S;
  constexpr int SAMPLES = 1 << S;
  constexpr int OFF = (S == 0) ? 0 : (S == 1 ? 128 : 192);
  constexpr int NK = K / 32;
  constexpr float INVD = 1.f / (float)(TK * 128);

  __shared__ unsigned short HT[128 * 128];
  __shared__ float scr[288];
  // scr: [0..127] fcw, [128..255] part, [256..287] per-(wave,group) stat slots
  float* part = scr + 128;

  const int tid = threadIdx.x, wave = tid >> 6, lane = tid & 63;
  const int quad = lane >> 4, l16 = lane & 15;
  const int n0 = blockIdx.x << S;
  const size_t xbase = (size_t)n0 * 16384;
  const int fo0 = (wave * 2) * 16 + l16;
  const int fo1 = (wave * 2 + 1) * 16 + l16;
  const int kf0 = (fo0 ^ (fo0 >> 3)) & 15;
  const int kf1 = (fo1 ^ (fo1 >> 3)) & 15;

  if (tid < 128) { scr[tid] = fc_w[tid]; part[tid] = 0.f; }

  // ---- conv (barrier-free) ----
  f32x4 acc[8][2];
#pragma unroll
  for (int tt = 0; tt < 8; ++tt) {
    acc[tt][0] = (f32x4){0.f, 0.f, 0.f, 0.f};
    acc[tt][1] = (f32x4){0.f, 0.f, 0.f, 0.f};
  }
#pragma unroll
  for (int ks = 0; ks < NK; ++ks) {
    short8 b0 = *(const short8*)&cwLT[fo0 * K + ks * 32 + quad * 8];
    short8 b1 = *(const short8*)&cwLT[fo1 * K + ks * 32 + quad * 8];
    short8 a[8];
#pragma unroll
    for (int tt = 0; tt < 8; ++tt) {
      size_t off = xbase + (size_t)(tt * 16 + l16) * K + ks * 32 + quad * 8;
      if constexpr (XBF) a[tt] = *(const short8*)&xb[off];
      else a[tt] = ldcvt8(xf + off);
    }
#pragma unroll
    for (int tt = 0; tt < 8; ++tt) {
      acc[tt][0] = __builtin_amdgcn_mfma_f32_16x16x32_bf16(a[tt], b0, acc[tt][0], 0, 0, 0);
      acc[tt][1] = __builtin_amdgcn_mfma_f32_16x16x32_bf16(a[tt], b1, acc[tt][1], 0, 0, 0);
    }
  }

  // ---- +cb, per-sample stats (wave partials over own 32 f-columns) ----
  const float cbv0 = cb[fo0], cbv1 = cb[fo1];
  {
    float gs[SAMPLES], gq[SAMPLES];
#pragma unroll
    for (int g = 0; g < SAMPLES; ++g) { gs[g] = 0.f; gq[g] = 0.f; }
#pragma unroll
    for (int tt = 0; tt < 8; ++tt) {
      int g = tt >> GSH;
#pragma unroll
      for (int r = 0; r < 4; ++r) {
        float v0 = acc[tt][0][r] + cbv0;
        float v1 = acc[tt][1][r] + cbv1;
        acc[tt][0][r] = v0; acc[tt][1][r] = v1;
        gs[g] += v0 + v1; gq[g] += v0 * v0 + v1 * v1;
      }
    }
#pragma unroll
    for (int g = 0; g < SAMPLES; ++g) {
      float s = gs[g], q = gq[g];
#pragma unroll
      for (int m = 32; m >= 1; m >>= 1) { s += __shfl_xor(s, m); q += __shfl_xor(q, m); }
      if (lane == 0) {
        scr[256 + (wave * SAMPLES + g) * 2] = s;
        scr[257 + (wave * SAMPLES + g) * 2] = q;
      }
    }
  }
  __syncthreads();   // barrier 1

  float mu[SAMPLES], rs[SAMPLES];
#pragma unroll
  for (int g = 0; g < SAMPLES; ++g) {
    float s = 0.f, q = 0.f;
#pragma unroll
    for (int w = 0; w < 4; ++w) {
      s += scr[256 + (w * SAMPLES + g) * 2];
      q += scr[257 + (w * SAMPLES + g) * 2];
    }
    float m = s * INVD;
    mu[g] = m; rs[g] = rsqrtf(q * INVD - m * m + 1e-5f);
  }

  // ---- fc contribution of xt ----
#pragma unroll
  for (int tt = 0; tt < 8; ++tt)
#pragma unroll
    for (int r = 0; r < 4; ++r) {
      float v = acc[tt][0][r] * scr[fo0] + acc[tt][1][r] * scr[fo1];
      v += __shfl_xor(v, 1); v += __shfl_xor(v, 2);
      v += __shfl_xor(v, 4); v += __shfl_xor(v, 8);
      if (l16 == 0) atomicAdd(&part[tt * 16 + quad * 4 + r], v);
    }

  // ---- LN -> HT (wave-private columns, XOR-swizzled; releases acc) ----
#pragma unroll
  for (int tt = 0; tt < 8; ++tt) {
    int g = tt >> GSH;
    int tb = tt * 16 + quad * 4;
    int tlb = tb & (TK - 1);
#pragma unroll
    for (int oo = 0; oo < 2; ++oo) {
      int f = oo ? fo1 : fo0;
      int kf = oo ? kf1 : kf0;
      float4 lg4 = *(const float4*)&lgT[f * TK + tlb];
      float4 lb4 = *(const float4*)&lbT[f * TK + tlb];
#pragma unroll
      for (int r = 0; r < 4; ++r) {
        int t = tb + r;
        float hv = (acc[tt][oo][r] - mu[g]) * rs[g] * (&lg4.x)[r] + (&lb4.x)[r];
        HT[f * 128 + ((((t >> 3) ^ kf) << 3) | (t & 7))] = f2bf(hv);
      }
    }
  }

  // ---- TM1 (no barrier: self-owned columns) ----
  f32x4 u[8][2];
#pragma unroll
  for (int tt = 0; tt < 8; ++tt) {
    u[tt][0] = (f32x4){0.f, 0.f, 0.f, 0.f};
    u[tt][1] = (f32x4){0.f, 0.f, 0.f, 0.f};
  }
#pragma unroll
  for (int ks = 0; ks < 4; ++ks) {
    short8 a[8];
#pragma unroll
    for (int tt = 0; tt < 8; ++tt) {
      constexpr int dummy = 0; (void)dummy;
      int g = tt >> GSH;
      bool act = (ks * 32 <= tt * 16 + 15) && (ks * 32 + 32 > (g << L2TK));
      if (act) a[tt] = *(const short8*)&L1blk[(tt * 16 + l16) * 128 + ks * 32 + quad * 8];
    }
    short8 b0 = *(const short8*)&HT[fo0 * 128 + (((ks * 4 + quad) ^ kf0) << 3)];
    short8 b1 = *(const short8*)&HT[fo1 * 128 + (((ks * 4 + quad) ^ kf1) << 3)];
#pragma unroll
    for (int tt = 0; tt < 8; ++tt) {
      int g = tt >> GSH;
      bool act = (ks * 32 <= tt * 16 + 15) && (ks * 32 + 32 > (g << L2TK));
      if (act) {
        u[tt][0] = __builtin_amdgcn_mfma_f32_16x16x32_bf16(a[tt], b0, u[tt][0], 0, 0, 0);
        u[tt][1] = __builtin_amdgcn_mfma_f32_16x16x32_bf16(a[tt], b1, u[tt][1], 0, 0, 0);
      }
    }
  }

  // ---- hswish -> UT (self-owned, no barrier) ----
#pragma unroll
  for (int tt = 0; tt < 8; ++tt) {
    int tb = tt * 16 + quad * 4;
#pragma unroll
    for (int oo = 0; oo < 2; ++oo) {
      int f = oo ? fo1 : fo0;
      int kf = oo ? kf1 : kf0;
#pragma unroll
      for (int r = 0; r < 4; ++r) {
        int t = tb + r;
        HT[f * 128 + ((((t >> 3) ^ kf) << 3) | (t & 7))] = f2bf(hswish(u[tt][oo][r]));
      }
    }
  }

  // ---- TM2 (no barrier) ----
#pragma unroll
  for (int tt = 0; tt < 8; ++tt) {
    u[tt][0] = (f32x4){0.f, 0.f, 0.f, 0.f};
    u[tt][1] = (f32x4){0.f, 0.f, 0.f, 0.f};
  }
#pragma unroll
  for (int ks = 0; ks < 4; ++ks) {
    short8 a[8];
#pragma unroll
    for (int tt = 0; tt < 8; ++tt) {
      int g = tt >> GSH;
      bool act = (ks * 32 <= tt * 16 + 15) && (ks * 32 + 32 > (g << L2TK));
      if (act) a[tt] = *(const short8*)&L2blk[(tt * 16 + l16) * 128 + ks * 32 + quad * 8];
    }
    short8 b0 = *(const short8*)&HT[fo0 * 128 + (((ks * 4 + quad) ^ kf0) << 3)];
    short8 b1 = *(const short8*)&HT[fo1 * 128 + (((ks * 4 + quad) ^ kf1) << 3)];
#pragma unroll
    for (int tt = 0; tt < 8; ++tt) {
      int g = tt >> GSH;
      bool act = (ks * 32 <= tt * 16 + 15) && (ks * 32 + 32 > (g << L2TK));
      if (act) {
        u[tt][0] = __builtin_amdgcn_mfma_f32_16x16x32_bf16(a[tt], b0, u[tt][0], 0, 0, 0);
        u[tt][1] = __builtin_amdgcn_mfma_f32_16x16x32_bf16(a[tt], b1, u[tt][1], 0, 0, 0);
      }
    }
  }

  // ---- fc contribution of v ----
#pragma unroll
  for (int tt = 0; tt < 8; ++tt)
#pragma unroll
    for (int r = 0; r < 4; ++r) {
      float v = u[tt][0][r] * scr[fo0] + u[tt][1][r] * scr[fo1];
      v += __shfl_xor(v, 1); v += __shfl_xor(v, 2);
      v += __shfl_xor(v, 4); v += __shfl_xor(v, 8);
      if (l16 == 0) atomicAdd(&part[tt * 16 + quad * 4 + r], v);
    }
  __syncthreads();   // barrier 2

  // ---- output + global stats contribution ----
  if (tid < 128) {
    float val = part[tid] + fc_b[0];
    int g = tid >> L2TK, tl = tid & (TK - 1);
    h_out[(size_t)(n0 + g) * 224 + OFF + tl] = val;
    float s = val, q = val * val;
#pragma unroll
    for (int m = 32; m >= 1; m >>= 1) { s += __shfl_xor(s, m); q += __shfl_xor(q, m); }
    if (lane == 0) {
      int slot = blockIdx.x & 31;
      atomicAdd(&stats[2 * slot], s);
      atomicAdd(&stats[2 * slot + 1], q);
    }
  }
}

// ---------------------------------------------------------------------------
// Stage 2
// ---------------------------------------------------------------------------
__global__ void mix1_kernel(const float* __restrict__ h,
                            const float* __restrict__ sm_lg,
                            const float* __restrict__ sm_lb,
                            const float* __restrict__ m1t,
                            const float* __restrict__ stats,
                            float* __restrict__ A) {
  const int m = blockIdx.x;
  const int r = threadIdx.x & 63, c = threadIdx.x >> 6;
  float S = 0.f, Q = 0.f;
#pragma unroll
  for (int s = 0; s < 32; ++s) { S += stats[2 * s]; Q += stats[2 * s + 1]; }
  const float inv = 1.f / 917504.f;
  float mu = S * inv;
  float rsig = rsqrtf(Q * inv - mu * mu + 1e-5f);
  float acc = 0.f;
  for (int i = 0; i < 1024; ++i) {
    int n = c * 1024 + i;
    float hn = (h[n * 224 + m] - mu) * rsig * sm_lg[n * 224 + m] + sm_lb[n * 224 + m];
    acc += m1t[n * 64 + r] * hn;
  }
  __shared__ float red[256];
  red[threadIdx.x] = acc;
  __syncthreads();
  if (threadIdx.x < 64)
    A[threadIdx.x * 224 + m] =
        red[threadIdx.x] + red[64 + threadIdx.x] + red[128 + threadIdx.x] + red[192 + threadIdx.x];
}

__global__ void mix2_kernel(const float* __restrict__ A,
                            const float* __restrict__ sm_fc_w,
                            float* __restrict__ cvec) {
  int r = threadIdx.x & 63, ch = threadIdx.x >> 6;
  float acc = 0.f;
  for (int j = ch; j < 224; j += 4)
    acc += hswish(A[r * 224 + j]) * sm_fc_w[224 + j];
  __shared__ float red[256];
  red[threadIdx.x] = acc;
  __syncthreads();
  if (threadIdx.x < 64)
    cvec[threadIdx.x] = red[threadIdx.x] + red[64 + threadIdx.x] + red[128 + threadIdx.x] + red[192 + threadIdx.x];
}

__global__ void out_kernel(const float* __restrict__ h,
                           const float* __restrict__ M2,
                           const float* __restrict__ cvec,
                           const float* __restrict__ sm_fc_w,
                           const float* __restrict__ sm_fc_b,
                           float* __restrict__ out) {
  int wave = threadIdx.x >> 6, lane = threadIdx.x & 63;
  int n = blockIdx.x * 4 + wave;
  float acc = M2[n * 64 + lane] * cvec[lane];
  for (int j = lane; j < 224; j += 64)
    acc += h[n * 224 + j] * (sm_fc_w[j] + sm_fc_w[224 + j]);
#pragma unroll
  for (int m = 32; m >= 1; m >>= 1) acc += __shfl_xor(acc, m);
  if (lane == 0) out[n] = acc + sm_fc_b[0];
}

// ---------------------------------------------------------------------------
extern "C" void kernel_launch(void* const* d_in, const int* in_sizes, int n_in,
                              void* d_out, int out_size, void* d_ws, size_t ws_size,
                              hipStream_t stream) {
  const float* x      = (const float*)d_in[0];
  const float* cw0    = (const float*)d_in[1];
  const float* cb0    = (const float*)d_in[2];
  const float* lg0    = (const float*)d_in[3];
  const float* lb0    = (const float*)d_in[4];
  const float* L1_0   = (const float*)d_in[5];
  const float* L2_0   = (const float*)d_in[6];
  const float* cw1    = (const float*)d_in[7];
  const float* cb1    = (const float*)d_in[8];
  const float* lg1    = (const float*)d_in[9];
  const float* lb1    = (const float*)d_in[10];
  const float* L1_1   = (const float*)d_in[11];
  const float* L2_1   = (const float*)d_in[12];
  const float* cw2    = (const float*)d_in[13];
  const float* cb2    = (const float*)d_in[14];
  const float* lg2    = (const float*)d_in[15];
  const float* lb2    = (const float*)d_in[16];
  const float* L1_2   = (const float*)d_in[17];
  const float* L2_2   = (const float*)d_in[18];
  const float* fc_w   = (const float*)d_in[19];
  const float* fc_b   = (const float*)d_in[20];
  const float* sm_lg  = (const float*)d_in[21];
  const float* sm_lb  = (const float*)d_in[22];
  const float* M1     = (const float*)d_in[23];
  const float* M2     = (const float*)d_in[24];
  const float* sm_fc_w = (const float*)d_in[25];
  const float* sm_fc_b = (const float*)d_in[26];

  char* ws = (char*)d_ws;
  unsigned short* ws16 = (unsigned short*)(ws + WS16_OFF);
  float* m1t   = (float*)(ws + M1T_OFF);
  float* lgT0  = (float*)(ws + LGT0_OFF); float* lbT0 = (float*)(ws + LBT0_OFF);
  float* lgT1  = (float*)(ws + LGT1_OFF); float* lbT1 = (float*)(ws + LBT1_OFF);
  float* lgT2  = (float*)(ws + LGT2_OFF); float* lbT2 = (float*)(ws + LBT2_OFF);
  float* h     = (float*)(ws + H_OFF);
  float* stats = (float*)(ws + STATS_OFF);
  float* A     = (float*)(ws + A_OFF);
  float* cvec  = (float*)(ws + CVEC_OFF);
  unsigned short* xbf = (unsigned short*)(ws + XBF_OFF);
  const bool use_xbf = ws_size >= WS_NEED;

  const unsigned short* cwLT0 = ws16;
  const unsigned short* cwLT1 = ws16 + 16384;
  const unsigned short* cwLT2 = ws16 + 49152;
  const unsigned short* L1b0 = ws16 + 114688;
  const unsigned short* L2b0 = ws16 + 131072;
  const unsigned short* L1b1 = ws16 + 147456;
  const unsigned short* L2b1 = ws16 + 163840;
  const unsigned short* L1b2 = ws16 + 180224;
  const unsigned short* L2b2 = ws16 + 196608;

  prep_kernel<<<2080, 256, 0, stream>>>(cw0, cw1, cw2, L1_0, L2_0, L1_1, L2_1, L1_2, L2_2,
                                        M1, lg0, lb0, lg1, lb1, lg2, lb2, ws);
  hipMemsetAsync(stats, 0, 256, stream);

  if (use_xbf) {
    xcvt_kernel<<<16384, 256, 0, stream>>>(x, xbf);
    s1_wp<0, true><<<4096, 256, 0, stream>>>(x, xbf, cb0, lgT0, lbT0, fc_w, fc_b, cwLT0, L1b0, L2b0, h, stats);
    s1_wp<1, true><<<2048, 256, 0, stream>>>(x, xbf, cb1, lgT1, lbT1, fc_w, fc_b, cwLT1, L1b1, L2b1, h, stats);
    s1_wp<2, true><<<1024, 256, 0, stream>>>(x, xbf, cb2, lgT2, lbT2, fc_w, fc_b, cwLT2, L1b2, L2b2, h, stats);
  } else {
    s1_wp<0, false><<<4096, 256, 0, stream>>>(x, xbf, cb0, lgT0, lbT0, fc_w, fc_b, cwLT0, L1b0, L2b0, h, stats);
    s1_wp<1, false><<<2048, 256, 0, stream>>>(x, xbf, cb1, lgT1, lbT1, fc_w, fc_b, cwLT1, L1b1, L2b1, h, stats);
    s1_wp<2, false><<<1024, 256, 0, stream>>>(x, xbf, cb2, lgT2, lbT2, fc_w, fc_b, cwLT2, L1b2, L2b2, h, stats);
  }

  mix1_kernel<<<224, 256, 0, stream>>>(h, sm_lg, sm_lb, m1t, stats, A);
  mix2_kernel<<<1, 256, 0, stream>>>(A, sm_fc_w, cvec);
  out_kernel<<<1024, 256, 0, stream>>>(h, M2, cvec, sm_fc_w, sm_fc_b, (float*)d_out);
}

// Round 5
// 999.081 us; speedup vs baseline: 1.1987x; 1.1987x over previous
//
#include <hip/hip_runtime.h>
#include <stdint.h>

typedef __attribute__((ext_vector_type(8))) short short8;
typedef __attribute__((ext_vector_type(4))) float f32x4;
typedef __attribute__((ext_vector_type(4))) unsigned short us4;

__device__ __forceinline__ unsigned short f2bf(float f) {
  union { float f; unsigned int i; } v; v.f = f;
  return (unsigned short)((v.i + 0x7FFFu + ((v.i >> 16) & 1u)) >> 16);
}
__device__ __forceinline__ float hswish(float x) {
  float t = fminf(fmaxf(x + 3.f, 0.f), 6.f);
  return x * t * (1.f / 6.f);
}
__device__ __forceinline__ short8 ldcvt8(const float* __restrict__ p) {
  float4 v0 = *(const float4*)p;
  float4 v1 = *(const float4*)(p + 4);
  short8 r;
  r[0] = (short)f2bf(v0.x); r[1] = (short)f2bf(v0.y);
  r[2] = (short)f2bf(v0.z); r[3] = (short)f2bf(v0.w);
  r[4] = (short)f2bf(v1.x); r[5] = (short)f2bf(v1.y);
  r[6] = (short)f2bf(v1.z); r[7] = (short)f2bf(v1.w);
  return r;
}

// ws byte offsets
#define WS16_OFF   0ULL          // bf16 weights: 425984 B
#define M1T_OFF    425984ULL     // fp32 4096x64
#define LGT0_OFF   1474560ULL    // fp32 128x128
#define LBT0_OFF   1540096ULL
#define LGT1_OFF   1605632ULL    // fp32 128x64
#define LBT1_OFF   1638400ULL
#define LGT2_OFF   1671168ULL    // fp32 128x32
#define LBT2_OFF   1687552ULL
#define H_OFF      1703936ULL    // fp32 4096x224
#define HT_OFF     5373952ULL    // fp32 224x4096
#define STATS_OFF  9043968ULL    // 64 floats
#define A_OFF      9044224ULL    // fp32 64x224
#define CVEC_OFF   9101568ULL    // 64 floats
#define XBF_OFF    9437184ULL    // bf16 4096x16384 = 134217728 B
#define WS_NEED    143654912ULL

// ---------------------------------------------------------------------------
// Prep: weights->bf16 (cwLT m=j*128+i; L1/L2 block-diag tril 128x128),
//       M1 transpose, lg/lb transpose
// ---------------------------------------------------------------------------
__global__ void prep_kernel(const float* __restrict__ cw0, const float* __restrict__ cw1,
                            const float* __restrict__ cw2,
                            const float* __restrict__ L1_0, const float* __restrict__ L2_0,
                            const float* __restrict__ L1_1, const float* __restrict__ L2_1,
                            const float* __restrict__ L1_2, const float* __restrict__ L2_2,
                            const float* __restrict__ M1,
                            const float* __restrict__ lg0, const float* __restrict__ lb0,
                            const float* __restrict__ lg1, const float* __restrict__ lb1,
                            const float* __restrict__ lg2, const float* __restrict__ lb2,
                            char* __restrict__ ws) {
  unsigned short* ws16 = (unsigned short*)(ws + WS16_OFF);
  float* m1t  = (float*)(ws + M1T_OFF);
  float* lgT0 = (float*)(ws + LGT0_OFF); float* lbT0 = (float*)(ws + LBT0_OFF);
  float* lgT1 = (float*)(ws + LGT1_OFF); float* lbT1 = (float*)(ws + LBT1_OFF);
  float* lgT2 = (float*)(ws + LGT2_OFF); float* lbT2 = (float*)(ws + LBT2_OFF);
  int idx = blockIdx.x * 256 + threadIdx.x;
  if (idx < 16384) {
    ws16[idx] = f2bf(cw0[idx]);
  } else if (idx < 49152) {
    int t = idx - 16384; int o = t >> 8, m = t & 255, j = m >> 7, i = m & 127;
    ws16[idx] = f2bf(cw1[(o * 128 + i) * 2 + j]);
  } else if (idx < 114688) {
    int t = idx - 49152; int o = t >> 9, m = t & 511, j = m >> 7, i = m & 127;
    ws16[idx] = f2bf(cw2[(o * 128 + i) * 4 + j]);
  } else if (idx < 212992) {
    int u = idx - 114688; int which = u >> 14; int e = u & 16383;
    int t = e >> 7, s = e & 127;
    float val = 0.f;
    if (which == 0)      { if (s <= t) val = L1_0[t * 128 + s]; }
    else if (which == 1) { if (s <= t) val = L2_0[t * 128 + s]; }
    else if (which == 2) { if ((s >> 6) == (t >> 6) && (s & 63) <= (t & 63)) val = L1_1[(t & 63) * 64 + (s & 63)]; }
    else if (which == 3) { if ((s >> 6) == (t >> 6) && (s & 63) <= (t & 63)) val = L2_1[(t & 63) * 64 + (s & 63)]; }
    else if (which == 4) { if ((s >> 5) == (t >> 5) && (s & 31) <= (t & 31)) val = L1_2[(t & 31) * 32 + (s & 31)]; }
    else                 { if ((s >> 5) == (t >> 5) && (s & 31) <= (t & 31)) val = L2_2[(t & 31) * 32 + (s & 31)]; }
    ws16[idx] = f2bf(val);
  } else if (idx < 475136) {
    int e = idx - 212992; int n = e >> 6, r = e & 63;
    m1t[e] = M1[r * 4096 + n];
  } else if (idx < 491520) {
    int e = idx - 475136; int f = e >> 7, t = e & 127; lgT0[e] = lg0[t * 128 + f];
  } else if (idx < 507904) {
    int e = idx - 491520; int f = e >> 7, t = e & 127; lbT0[e] = lb0[t * 128 + f];
  } else if (idx < 516096) {
    int e = idx - 507904; int f = e >> 6, t = e & 63;  lgT1[e] = lg1[t * 128 + f];
  } else if (idx < 524288) {
    int e = idx - 516096; int f = e >> 6, t = e & 63;  lbT1[e] = lb1[t * 128 + f];
  } else if (idx < 528384) {
    int e = idx - 524288; int f = e >> 5, t = e & 31;  lgT2[e] = lg2[t * 128 + f];
  } else if (idx < 532480) {
    int e = idx - 528384; int f = e >> 5, t = e & 31;  lbT2[e] = lb2[t * 128 + f];
  }
}

// x (fp32) -> xbf (bf16)
__global__ void xcvt_kernel(const float* __restrict__ x, unsigned short* __restrict__ xbf) {
  const float4* x4 = (const float4*)x;
  us4* o4 = (us4*)xbf;
#pragma unroll
  for (int j = 0; j < 4; ++j) {
    int idx = blockIdx.x * 1024 + j * 256 + threadIdx.x;
    float4 v = x4[idx];
    us4 p; p[0] = f2bf(v.x); p[1] = f2bf(v.y); p[2] = f2bf(v.z); p[3] = f2bf(v.w);
    o4[idx] = p;
  }
}

// ---------------------------------------------------------------------------
// Stage-1 body: r3 partitioning (wave = 4 t-tiles x 4 o-tiles, 2x2 split).
// One block = 128 output rows = 2^S samples.
// ---------------------------------------------------------------------------
template <int S, bool XBF>
__device__ __forceinline__ void s1_body(
    int bidx,
    const float* __restrict__ xf, const unsigned short* __restrict__ xb,
    const float* __restrict__ cb, const float* __restrict__ lgT, const float* __restrict__ lbT,
    const float* __restrict__ fc_w, const float* __restrict__ fc_b,
    const unsigned short* __restrict__ cwLT,
    const unsigned short* __restrict__ L1blk, const unsigned short* __restrict__ L2blk,
    float* __restrict__ h_out, float* __restrict__ hT, float* __restrict__ stats,
    unsigned short* __restrict__ HT, float* __restrict__ scr) {
  constexpr int K = 128 << S;
  constexpr int LOG2TK = 7 - S;
  constexpr int TKM = (128 >> S) - 1;
  constexpr int TK = 128 >> S;
  constexpr int SAMPLES = 1 << S;
  constexpr int OFF = (S == 0) ? 0 : (S == 1 ? 128 : 192);
  constexpr int NK = K / 32;
  constexpr int GSH = 3 - S;
  constexpr float INVD = 1.f / (float)(TK * 128);

  float* part = scr + 128;
  const int tid = threadIdx.x, wave = tid >> 6, lane = tid & 63;
  const int quad = lane >> 4, l16 = lane & 15;
  const int Tb = (wave & 1) * 4, Ob = (wave >> 1) * 4;
  const int n0 = bidx << S;
  const size_t xbase = (size_t)n0 * 16384;

  if (tid < 128) { scr[tid] = fc_w[tid]; part[tid] = 0.f; }
  else if (tid < 144) scr[tid + 128] = 0.f;   // scr[256..271]
  __syncthreads();

  // ---- conv (barrier-free) ----
  f32x4 acc[4][4];
#pragma unroll
  for (int tt = 0; tt < 4; ++tt)
#pragma unroll
    for (int oo = 0; oo < 4; ++oo) acc[tt][oo] = (f32x4){0.f, 0.f, 0.f, 0.f};
#pragma unroll 4
  for (int ks = 0; ks < NK; ++ks) {
    short8 a[4];
#pragma unroll
    for (int tt = 0; tt < 4; ++tt) {
      size_t off = xbase + (size_t)((Tb + tt) * 16 + l16) * K + ks * 32 + quad * 8;
      if constexpr (XBF) a[tt] = *(const short8*)&xb[off];
      else a[tt] = ldcvt8(xf + off);
    }
#pragma unroll
    for (int oo = 0; oo < 4; ++oo) {
      short8 b = *(const short8*)&cwLT[((Ob + oo) * 16 + l16) * K + ks * 32 + quad * 8];
#pragma unroll
      for (int tt = 0; tt < 4; ++tt)
        acc[tt][oo] = __builtin_amdgcn_mfma_f32_16x16x32_bf16(a[tt], b, acc[tt][oo], 0, 0, 0);
    }
  }

  // ---- +cb, per-sample LN stats ----
  float ts[4] = {0.f, 0.f, 0.f, 0.f}, tq[4] = {0.f, 0.f, 0.f, 0.f};
#pragma unroll
  for (int oo = 0; oo < 4; ++oo) {
    float cbv = cb[(Ob + oo) * 16 + l16];
#pragma unroll
    for (int tt = 0; tt < 4; ++tt)
#pragma unroll
      for (int r = 0; r < 4; ++r) {
        float v = acc[tt][oo][r] + cbv;
        acc[tt][oo][r] = v;
        ts[tt] += v; tq[tt] += v * v;
      }
  }
  {
    constexpr int GPW = (S == 2) ? 2 : 1;
    float gs[2] = {0.f, 0.f}, gq[2] = {0.f, 0.f};
#pragma unroll
    for (int tt = 0; tt < 4; ++tt) {
      int gl = (S == 2) ? (tt >> 1) : 0;
      gs[gl] += ts[tt]; gq[gl] += tq[tt];
    }
#pragma unroll
    for (int j = 0; j < GPW; ++j) {
      float s = gs[j], q = gq[j];
#pragma unroll
      for (int m = 32; m >= 1; m >>= 1) { s += __shfl_xor(s, m); q += __shfl_xor(q, m); }
      if (lane == 0) {
        int g = (Tb >> GSH) + j;
        atomicAdd(&scr[256 + 2 * g], s);
        atomicAdd(&scr[257 + 2 * g], q);
      }
    }
  }
  __syncthreads();
  if (tid < SAMPLES) {
    float mu = scr[256 + 2 * tid] * INVD;
    float var = scr[257 + 2 * tid] * INVD - mu * mu;
    scr[264 + tid] = mu; scr[268 + tid] = rsqrtf(var + 1e-5f);
  }
  __syncthreads();

  // ---- fc contribution of xt ----
#pragma unroll
  for (int tt = 0; tt < 4; ++tt)
#pragma unroll
    for (int r = 0; r < 4; ++r) {
      float v = 0.f;
#pragma unroll
      for (int oo = 0; oo < 4; ++oo) v += acc[tt][oo][r] * scr[(Ob + oo) * 16 + l16];
      v += __shfl_xor(v, 1); v += __shfl_xor(v, 2);
      v += __shfl_xor(v, 4); v += __shfl_xor(v, 8);
      if (l16 == 0) atomicAdd(&part[(Tb + tt) * 16 + quad * 4 + r], v);
    }

  // ---- HT[f][t] = bf16(LN(xt)), XOR-swizzled ----
#pragma unroll
  for (int tt = 0; tt < 4; ++tt) {
    int tile = Tb + tt, g = tile >> GSH;
    float mu = scr[264 + g], rs = scr[268 + g];
    int tb = tile * 16 + quad * 4;
    int tl = tb & TKM;
#pragma unroll
    for (int oo = 0; oo < 4; ++oo) {
      int f = (Ob + oo) * 16 + l16;
      int kf = (f ^ (f >> 3)) & 15;
      float4 lg4 = *(const float4*)&lgT[f * TK + tl];
      float4 lb4 = *(const float4*)&lbT[f * TK + tl];
#pragma unroll
      for (int r = 0; r < 4; ++r) {
        int t = tb + r;
        float hv = (acc[tt][oo][r] - mu) * rs * (&lg4.x)[r] + (&lb4.x)[r];
        HT[f * 128 + ((((t >> 3) ^ kf) << 3) | (t & 7))] = f2bf(hv);
      }
    }
  }
  __syncthreads();

  // ---- TM1: U = blkdiag_tril(L1) @ H ----
  f32x4 u[4][4];
#pragma unroll
  for (int tt = 0; tt < 4; ++tt)
#pragma unroll
    for (int oo = 0; oo < 4; ++oo) u[tt][oo] = (f32x4){0.f, 0.f, 0.f, 0.f};
#pragma unroll
  for (int ks = 0; ks < 4; ++ks) {
    short8 a[4]; bool act[4]; bool any = false;
#pragma unroll
    for (int tt = 0; tt < 4; ++tt) {
      int tile = Tb + tt, g = tile >> GSH;
      act[tt] = (ks * 32 <= tile * 16 + 15) && (ks * 32 + 31 >= (g << LOG2TK));
      if (act[tt]) { a[tt] = *(const short8*)&L1blk[(tile * 16 + l16) * 128 + ks * 32 + quad * 8]; any = true; }
    }
    if (!any) continue;
#pragma unroll
    for (int oo = 0; oo < 4; ++oo) {
      int f = (Ob + oo) * 16 + l16;
      int kf = (f ^ (f >> 3)) & 15;
      short8 b = *(const short8*)&HT[f * 128 + (((ks * 4 + quad) ^ kf) << 3)];
#pragma unroll
      for (int tt = 0; tt < 4; ++tt)
        if (act[tt]) u[tt][oo] = __builtin_amdgcn_mfma_f32_16x16x32_bf16(a[tt], b, u[tt][oo], 0, 0, 0);
    }
  }
  __syncthreads();

  // ---- UT = bf16(hswish(U)) ----
#pragma unroll
  for (int tt = 0; tt < 4; ++tt) {
    int tile = Tb + tt;
    int tb = tile * 16 + quad * 4;
#pragma unroll
    for (int oo = 0; oo < 4; ++oo) {
      int f = (Ob + oo) * 16 + l16;
      int kf = (f ^ (f >> 3)) & 15;
#pragma unroll
      for (int r = 0; r < 4; ++r) {
        int t = tb + r;
        HT[f * 128 + ((((t >> 3) ^ kf) << 3) | (t & 7))] = f2bf(hswish(u[tt][oo][r]));
      }
    }
  }
  __syncthreads();

  // ---- TM2: v = blkdiag_tril(L2) @ U ----
#pragma unroll
  for (int tt = 0; tt < 4; ++tt)
#pragma unroll
    for (int oo = 0; oo < 4; ++oo) u[tt][oo] = (f32x4){0.f, 0.f, 0.f, 0.f};
#pragma unroll
  for (int ks = 0; ks < 4; ++ks) {
    short8 a[4]; bool act[4]; bool any = false;
#pragma unroll
    for (int tt = 0; tt < 4; ++tt) {
      int tile = Tb + tt, g = tile >> GSH;
      act[tt] = (ks * 32 <= tile * 16 + 15) && (ks * 32 + 31 >= (g << LOG2TK));
      if (act[tt]) { a[tt] = *(const short8*)&L2blk[(tile * 16 + l16) * 128 + ks * 32 + quad * 8]; any = true; }
    }
    if (!any) continue;
#pragma unroll
    for (int oo = 0; oo < 4; ++oo) {
      int f = (Ob + oo) * 16 + l16;
      int kf = (f ^ (f >> 3)) & 15;
      short8 b = *(const short8*)&HT[f * 128 + (((ks * 4 + quad) ^ kf) << 3)];
#pragma unroll
      for (int tt = 0; tt < 4; ++tt)
        if (act[tt]) u[tt][oo] = __builtin_amdgcn_mfma_f32_16x16x32_bf16(a[tt], b, u[tt][oo], 0, 0, 0);
    }
  }

  // ---- fc contribution of v ----
#pragma unroll
  for (int tt = 0; tt < 4; ++tt)
#pragma unroll
    for (int r = 0; r < 4; ++r) {
      float v = 0.f;
#pragma unroll
      for (int oo = 0; oo < 4; ++oo) v += u[tt][oo][r] * scr[(Ob + oo) * 16 + l16];
      v += __shfl_xor(v, 1); v += __shfl_xor(v, 2);
      v += __shfl_xor(v, 4); v += __shfl_xor(v, 8);
      if (l16 == 0) atomicAdd(&part[(Tb + tt) * 16 + quad * 4 + r], v);
    }
  __syncthreads();

  // ---- output h, hT + global LN stats contribution ----
  if (tid < 128) {
    float val = part[tid] + fc_b[0];
    int g = tid >> LOG2TK, tl = tid & TKM;
    int n = n0 + g;
    h_out[(size_t)n * 224 + OFF + tl] = val;
    hT[(size_t)(OFF + tl) * 4096 + n] = val;
    float s = val, q = val * val;
#pragma unroll
    for (int m = 32; m >= 1; m >>= 1) { s += __shfl_xor(s, m); q += __shfl_xor(q, m); }
    if (lane == 0) {
      int slot = (int)(blockIdx.x & 31);
      atomicAdd(&stats[2 * slot], s);
      atomicAdd(&stats[2 * slot + 1], q);
    }
  }
}

template <bool XBF>
__launch_bounds__(256, 4)
__global__ void s1_all(const float* __restrict__ xf, const unsigned short* __restrict__ xb,
                       const float* __restrict__ cb0, const float* __restrict__ cb1,
                       const float* __restrict__ cb2,
                       const float* __restrict__ fc_w, const float* __restrict__ fc_b,
                       const char* __restrict__ wsc,
                       float* __restrict__ h_out, float* __restrict__ hT,
                       float* __restrict__ stats) {
  __shared__ unsigned short HT[128 * 128];
  __shared__ float scr[272];
  const unsigned short* ws16 = (const unsigned short*)(wsc + WS16_OFF);
  int b = blockIdx.x;
  if (b < 1024) {
    s1_body<2, XBF>(b, xf, xb, cb2,
                    (const float*)(wsc + LGT2_OFF), (const float*)(wsc + LBT2_OFF),
                    fc_w, fc_b, ws16 + 49152, ws16 + 180224, ws16 + 196608,
                    h_out, hT, stats, HT, scr);
  } else if (b < 3072) {
    s1_body<1, XBF>(b - 1024, xf, xb, cb1,
                    (const float*)(wsc + LGT1_OFF), (const float*)(wsc + LBT1_OFF),
                    fc_w, fc_b, ws16 + 16384, ws16 + 147456, ws16 + 163840,
                    h_out, hT, stats, HT, scr);
  } else {
    s1_body<0, XBF>(b - 3072, xf, xb, cb0,
                    (const float*)(wsc + LGT0_OFF), (const float*)(wsc + LBT0_OFF),
                    fc_w, fc_b, ws16, ws16 + 114688, ws16 + 131072,
                    h_out, hT, stats, HT, scr);
  }
}

// ---------------------------------------------------------------------------
// Stage 2
// ---------------------------------------------------------------------------
__global__ void mix1_kernel(const float* __restrict__ hT,
                            const float* __restrict__ sm_lg,
                            const float* __restrict__ sm_lb,
                            const float* __restrict__ m1t,
                            const float* __restrict__ stats,
                            float* __restrict__ A) {
  const int m = blockIdx.x;        // 0..223
  const int seg = blockIdx.y;      // 0..7
  const int r = threadIdx.x & 63, c = threadIdx.x >> 6;
  float S = 0.f, Q = 0.f;
#pragma unroll
  for (int s = 0; s < 32; ++s) { S += stats[2 * s]; Q += stats[2 * s + 1]; }
  const float inv = 1.f / 917504.f;
  float mu = S * inv;
  float rsig = rsqrtf(Q * inv - mu * mu + 1e-5f);
  float acc = 0.f;
  const int n0 = seg * 512 + c * 128;
  for (int i = 0; i < 128; ++i) {
    int n = n0 + i;
    float hn = (hT[m * 4096 + n] - mu) * rsig * sm_lg[n * 224 + m] + sm_lb[n * 224 + m];
    acc += m1t[n * 64 + r] * hn;
  }
  __shared__ float red[256];
  red[threadIdx.x] = acc;
  __syncthreads();
  if (threadIdx.x < 64)
    atomicAdd(&A[threadIdx.x * 224 + m],
              red[threadIdx.x] + red[64 + threadIdx.x] + red[128 + threadIdx.x] + red[192 + threadIdx.x]);
}

__global__ void mix2_kernel(const float* __restrict__ A,
                            const float* __restrict__ sm_fc_w,
                            float* __restrict__ cvec) {
  int r = threadIdx.x & 63, ch = threadIdx.x >> 6;
  float acc = 0.f;
  for (int j = ch; j < 224; j += 4)
    acc += hswish(A[r * 224 + j]) * sm_fc_w[224 + j];
  __shared__ float red[256];
  red[threadIdx.x] = acc;
  __syncthreads();
  if (threadIdx.x < 64)
    cvec[threadIdx.x] = red[threadIdx.x] + red[64 + threadIdx.x] + red[128 + threadIdx.x] + red[192 + threadIdx.x];
}

__global__ void out_kernel(const float* __restrict__ h,
                           const float* __restrict__ M2,
                           const float* __restrict__ cvec,
                           const float* __restrict__ sm_fc_w,
                           const float* __restrict__ sm_fc_b,
                           float* __restrict__ out) {
  int wave = threadIdx.x >> 6, lane = threadIdx.x & 63;
  int n = blockIdx.x * 4 + wave;
  float acc = M2[n * 64 + lane] * cvec[lane];
  for (int j = lane; j < 224; j += 64)
    acc += h[n * 224 + j] * (sm_fc_w[j] + sm_fc_w[224 + j]);
#pragma unroll
  for (int m = 32; m >= 1; m >>= 1) acc += __shfl_xor(acc, m);
  if (lane == 0) out[n] = acc + sm_fc_b[0];
}

// ---------------------------------------------------------------------------
extern "C" void kernel_launch(void* const* d_in, const int* in_sizes, int n_in,
                              void* d_out, int out_size, void* d_ws, size_t ws_size,
                              hipStream_t stream) {
  const float* x      = (const float*)d_in[0];
  const float* cw0    = (const float*)d_in[1];
  const float* cb0    = (const float*)d_in[2];
  const float* lg0    = (const float*)d_in[3];
  const float* lb0    = (const float*)d_in[4];
  const float* L1_0   = (const float*)d_in[5];
  const float* L2_0   = (const float*)d_in[6];
  const float* cw1    = (const float*)d_in[7];
  const float* cb1    = (const float*)d_in[8];
  const float* lg1    = (const float*)d_in[9];
  const float* lb1    = (const float*)d_in[10];
  const float* L1_1   = (const float*)d_in[11];
  const float* L2_1   = (const float*)d_in[12];
  const float* cw2    = (const float*)d_in[13];
  const float* cb2    = (const float*)d_in[14];
  const float* lg2    = (const float*)d_in[15];
  const float* lb2    = (const float*)d_in[16];
  const float* L1_2   = (const float*)d_in[17];
  const float* L2_2   = (const float*)d_in[18];
  const float* fc_w   = (const float*)d_in[19];
  const float* fc_b   = (const float*)d_in[20];
  const float* sm_lg  = (const float*)d_in[21];
  const float* sm_lb  = (const float*)d_in[22];
  const float* M1     = (const float*)d_in[23];
  const float* M2     = (const float*)d_in[24];
  const float* sm_fc_w = (const float*)d_in[25];
  const float* sm_fc_b = (const float*)d_in[26];

  char* ws = (char*)d_ws;
  float* m1t   = (float*)(ws + M1T_OFF);
  float* h     = (float*)(ws + H_OFF);
  float* hT    = (float*)(ws + HT_OFF);
  float* stats = (float*)(ws + STATS_OFF);
  float* A     = (float*)(ws + A_OFF);
  float* cvec  = (float*)(ws + CVEC_OFF);
  unsigned short* xbf = (unsigned short*)(ws + XBF_OFF);
  const bool use_xbf = ws_size >= WS_NEED;

  prep_kernel<<<2080, 256, 0, stream>>>(cw0, cw1, cw2, L1_0, L2_0, L1_1, L2_1, L1_2, L2_2,
                                        M1, lg0, lb0, lg1, lb1, lg2, lb2, ws);
  // zero stats + A in one memset (contiguous region)
  hipMemsetAsync(ws + STATS_OFF, 0, 256 + 57344, stream);

  if (use_xbf) {
    xcvt_kernel<<<16384, 256, 0, stream>>>(x, xbf);
    s1_all<true><<<7168, 256, 0, stream>>>(x, xbf, cb0, cb1, cb2, fc_w, fc_b, ws, h, hT, stats);
  } else {
    s1_all<false><<<7168, 256, 0, stream>>>(x, xbf, cb0, cb1, cb2, fc_w, fc_b, ws, h, hT, stats);
  }

  mix1_kernel<<<dim3(224, 8), 256, 0, stream>>>(hT, sm_lg, sm_lb, m1t, stats, A);
  mix2_kernel<<<1, 256, 0, stream>>>(A, sm_fc_w, cvec);
  out_kernel<<<1024, 256, 0, stream>>>(h, M2, cvec, sm_fc_w, sm_fc_b, (float*)d_out);
}

// Round 6
// 951.797 us; speedup vs baseline: 1.2582x; 1.0497x over previous
//
#include <hip/hip_runtime.h>
#include <stdint.h>

typedef __attribute__((ext_vector_type(8))) short short8;
typedef __attribute__((ext_vector_type(4))) float f32x4;
typedef __attribute__((ext_vector_type(4))) unsigned short us4;

__device__ __forceinline__ unsigned short f2bf(float f) {
  union { float f; unsigned int i; } v; v.f = f;
  return (unsigned short)((v.i + 0x7FFFu + ((v.i >> 16) & 1u)) >> 16);
}
__device__ __forceinline__ float hswish(float x) {
  float t = fminf(fmaxf(x + 3.f, 0.f), 6.f);
  return x * t * (1.f / 6.f);
}
__device__ __forceinline__ short8 ldcvt8(const float* __restrict__ p) {
  float4 v0 = *(const float4*)p;
  float4 v1 = *(const float4*)(p + 4);
  short8 r;
  r[0] = (short)f2bf(v0.x); r[1] = (short)f2bf(v0.y);
  r[2] = (short)f2bf(v0.z); r[3] = (short)f2bf(v0.w);
  r[4] = (short)f2bf(v1.x); r[5] = (short)f2bf(v1.y);
  r[6] = (short)f2bf(v1.z); r[7] = (short)f2bf(v1.w);
  return r;
}

// ws byte offsets
#define WS16_OFF   0ULL          // bf16 weights: 425984 B
#define M1T_OFF    425984ULL     // fp32 4096x64
#define LGT0_OFF   1474560ULL    // fp32 128x128
#define LBT0_OFF   1540096ULL
#define LGT1_OFF   1605632ULL    // fp32 128x64
#define LBT1_OFF   1638400ULL
#define LGT2_OFF   1671168ULL    // fp32 128x32
#define LBT2_OFF   1687552ULL
#define H_OFF      1703936ULL    // fp32 4096x224
#define STATS_OFF  5373952ULL    // 64 floats
#define A_OFF      5374208ULL    // fp32 64x224
#define CVEC_OFF   5431552ULL    // 64 floats
#define XBF_OFF    8388608ULL    // bf16 4096x16384 = 134217728 B
#define WS_NEED    142606336ULL

// ---------------------------------------------------------------------------
// Prep: weights->bf16 (cwLT m=j*128+i; L1/L2 block-diag tril 128x128),
//       M1 transpose, lg/lb transpose
// ---------------------------------------------------------------------------
__global__ void prep_kernel(const float* __restrict__ cw0, const float* __restrict__ cw1,
                            const float* __restrict__ cw2,
                            const float* __restrict__ L1_0, const float* __restrict__ L2_0,
                            const float* __restrict__ L1_1, const float* __restrict__ L2_1,
                            const float* __restrict__ L1_2, const float* __restrict__ L2_2,
                            const float* __restrict__ M1,
                            const float* __restrict__ lg0, const float* __restrict__ lb0,
                            const float* __restrict__ lg1, const float* __restrict__ lb1,
                            const float* __restrict__ lg2, const float* __restrict__ lb2,
                            char* __restrict__ ws) {
  unsigned short* ws16 = (unsigned short*)(ws + WS16_OFF);
  float* m1t  = (float*)(ws + M1T_OFF);
  float* lgT0 = (float*)(ws + LGT0_OFF); float* lbT0 = (float*)(ws + LBT0_OFF);
  float* lgT1 = (float*)(ws + LGT1_OFF); float* lbT1 = (float*)(ws + LBT1_OFF);
  float* lgT2 = (float*)(ws + LGT2_OFF); float* lbT2 = (float*)(ws + LBT2_OFF);
  int idx = blockIdx.x * 256 + threadIdx.x;
  if (idx < 16384) {
    ws16[idx] = f2bf(cw0[idx]);
  } else if (idx < 49152) {
    int t = idx - 16384; int o = t >> 8, m = t & 255, j = m >> 7, i = m & 127;
    ws16[idx] = f2bf(cw1[(o * 128 + i) * 2 + j]);
  } else if (idx < 114688) {
    int t = idx - 49152; int o = t >> 9, m = t & 511, j = m >> 7, i = m & 127;
    ws16[idx] = f2bf(cw2[(o * 128 + i) * 4 + j]);
  } else if (idx < 212992) {
    int u = idx - 114688; int which = u >> 14; int e = u & 16383;
    int t = e >> 7, s = e & 127;
    float val = 0.f;
    if (which == 0)      { if (s <= t) val = L1_0[t * 128 + s]; }
    else if (which == 1) { if (s <= t) val = L2_0[t * 128 + s]; }
    else if (which == 2) { if ((s >> 6) == (t >> 6) && (s & 63) <= (t & 63)) val = L1_1[(t & 63) * 64 + (s & 63)]; }
    else if (which == 3) { if ((s >> 6) == (t >> 6) && (s & 63) <= (t & 63)) val = L2_1[(t & 63) * 64 + (s & 63)]; }
    else if (which == 4) { if ((s >> 5) == (t >> 5) && (s & 31) <= (t & 31)) val = L1_2[(t & 31) * 32 + (s & 31)]; }
    else                 { if ((s >> 5) == (t >> 5) && (s & 31) <= (t & 31)) val = L2_2[(t & 31) * 32 + (s & 31)]; }
    ws16[idx] = f2bf(val);
  } else if (idx < 475136) {
    int e = idx - 212992; int n = e >> 6, r = e & 63;
    m1t[e] = M1[r * 4096 + n];
  } else if (idx < 491520) {
    int e = idx - 475136; int f = e >> 7, t = e & 127; lgT0[e] = lg0[t * 128 + f];
  } else if (idx < 507904) {
    int e = idx - 491520; int f = e >> 7, t = e & 127; lbT0[e] = lb0[t * 128 + f];
  } else if (idx < 516096) {
    int e = idx - 507904; int f = e >> 6, t = e & 63;  lgT1[e] = lg1[t * 128 + f];
  } else if (idx < 524288) {
    int e = idx - 516096; int f = e >> 6, t = e & 63;  lbT1[e] = lb1[t * 128 + f];
  } else if (idx < 528384) {
    int e = idx - 524288; int f = e >> 5, t = e & 31;  lgT2[e] = lg2[t * 128 + f];
  } else if (idx < 532480) {
    int e = idx - 528384; int f = e >> 5, t = e & 31;  lbT2[e] = lb2[t * 128 + f];
  }
}

// x (fp32) -> xbf (bf16)
__global__ void xcvt_kernel(const float* __restrict__ x, unsigned short* __restrict__ xbf) {
  const float4* x4 = (const float4*)x;
  us4* o4 = (us4*)xbf;
#pragma unroll
  for (int j = 0; j < 4; ++j) {
    int idx = blockIdx.x * 1024 + j * 256 + threadIdx.x;
    float4 v = x4[idx];
    us4 p; p[0] = f2bf(v.x); p[1] = f2bf(v.y); p[2] = f2bf(v.z); p[3] = f2bf(v.w);
    o4[idx] = p;
  }
}

// ---------------------------------------------------------------------------
// Stage 1 (r3 structure): one block = 128 output rows = 2^S samples.
// wave = 4 t-tiles x 4 o-tiles (2x2 wave split). 3 blocks/CU.
// ---------------------------------------------------------------------------
template <int S, bool XBF>
__launch_bounds__(256, 3)
__global__ void s1_tile(const float* __restrict__ xf, const unsigned short* __restrict__ xb,
                        const float* __restrict__ cb,
                        const float* __restrict__ lgT, const float* __restrict__ lbT,
                        const float* __restrict__ fc_w, const float* __restrict__ fc_b,
                        const unsigned short* __restrict__ cwLT,
                        const unsigned short* __restrict__ L1blk,
                        const unsigned short* __restrict__ L2blk,
                        float* __restrict__ h_out, float* __restrict__ stats) {
  constexpr int K = 128 << S;
  constexpr int LOG2TK = 7 - S;
  constexpr int TKM = (128 >> S) - 1;
  constexpr int TK = 128 >> S;
  constexpr int SAMPLES = 1 << S;
  constexpr int OFF = (S == 0) ? 0 : (S == 1 ? 128 : 192);
  constexpr int NK = K / 32;
  constexpr int GSH = 3 - S;
  constexpr float INVD = 1.f / (float)(TK * 128);

  __shared__ unsigned short HT[128 * 128];
  __shared__ float scr[272];
  // scr: [0..127] fcw, [128..255] part, [256..263] stat sums, [264..267] mu, [268..271] rsig
  float* part = scr + 128;

  const int tid = threadIdx.x, wave = tid >> 6, lane = tid & 63;
  const int quad = lane >> 4, l16 = lane & 15;
  const int Tb = (wave & 1) * 4, Ob = (wave >> 1) * 4;
  const int n0 = blockIdx.x << S;
  const size_t xbase = (size_t)n0 * 16384;

  if (tid < 128) { scr[tid] = fc_w[tid]; part[tid] = 0.f; }
  else if (tid < 144) scr[tid + 128] = 0.f;
  __syncthreads();

  // ---- conv (barrier-free) ----
  f32x4 acc[4][4];
#pragma unroll
  for (int tt = 0; tt < 4; ++tt)
#pragma unroll
    for (int oo = 0; oo < 4; ++oo) acc[tt][oo] = (f32x4){0.f, 0.f, 0.f, 0.f};
  for (int ks = 0; ks < NK; ++ks) {
    short8 a[4];
#pragma unroll
    for (int tt = 0; tt < 4; ++tt) {
      size_t off = xbase + (size_t)((Tb + tt) * 16 + l16) * K + ks * 32 + quad * 8;
      if constexpr (XBF) a[tt] = *(const short8*)&xb[off];
      else a[tt] = ldcvt8(xf + off);
    }
#pragma unroll
    for (int oo = 0; oo < 4; ++oo) {
      short8 b = *(const short8*)&cwLT[((Ob + oo) * 16 + l16) * K + ks * 32 + quad * 8];
#pragma unroll
      for (int tt = 0; tt < 4; ++tt)
        acc[tt][oo] = __builtin_amdgcn_mfma_f32_16x16x32_bf16(a[tt], b, acc[tt][oo], 0, 0, 0);
    }
  }

  // ---- +cb, per-sample LN stats ----
  float ts[4] = {0.f, 0.f, 0.f, 0.f}, tq[4] = {0.f, 0.f, 0.f, 0.f};
#pragma unroll
  for (int oo = 0; oo < 4; ++oo) {
    float cbv = cb[(Ob + oo) * 16 + l16];
#pragma unroll
    for (int tt = 0; tt < 4; ++tt)
#pragma unroll
      for (int r = 0; r < 4; ++r) {
        float v = acc[tt][oo][r] + cbv;
        acc[tt][oo][r] = v;
        ts[tt] += v; tq[tt] += v * v;
      }
  }
  {
    constexpr int GPW = (S == 2) ? 2 : 1;
    float gs[2] = {0.f, 0.f}, gq[2] = {0.f, 0.f};
#pragma unroll
    for (int tt = 0; tt < 4; ++tt) {
      int gl = (S == 2) ? (tt >> 1) : 0;
      gs[gl] += ts[tt]; gq[gl] += tq[tt];
    }
#pragma unroll
    for (int j = 0; j < GPW; ++j) {
      float s = gs[j], q = gq[j];
#pragma unroll
      for (int m = 32; m >= 1; m >>= 1) { s += __shfl_xor(s, m); q += __shfl_xor(q, m); }
      if (lane == 0) {
        int g = (Tb >> GSH) + j;
        atomicAdd(&scr[256 + 2 * g], s);
        atomicAdd(&scr[257 + 2 * g], q);
      }
    }
  }
  __syncthreads();
  if (tid < SAMPLES) {
    float mu = scr[256 + 2 * tid] * INVD;
    float var = scr[257 + 2 * tid] * INVD - mu * mu;
    scr[264 + tid] = mu; scr[268 + tid] = rsqrtf(var + 1e-5f);
  }
  __syncthreads();

  // ---- fc contribution of xt ----
#pragma unroll
  for (int tt = 0; tt < 4; ++tt)
#pragma unroll
    for (int r = 0; r < 4; ++r) {
      float v = 0.f;
#pragma unroll
      for (int oo = 0; oo < 4; ++oo) v += acc[tt][oo][r] * scr[(Ob + oo) * 16 + l16];
      v += __shfl_xor(v, 1); v += __shfl_xor(v, 2);
      v += __shfl_xor(v, 4); v += __shfl_xor(v, 8);
      if (l16 == 0) atomicAdd(&part[(Tb + tt) * 16 + quad * 4 + r], v);
    }

  // ---- HT[f][t] = bf16(LN(xt)), XOR-swizzled ----
#pragma unroll
  for (int tt = 0; tt < 4; ++tt) {
    int tile = Tb + tt, g = tile >> GSH;
    float mu = scr[264 + g], rs = scr[268 + g];
    int tb = tile * 16 + quad * 4;
    int tl = tb & TKM;
#pragma unroll
    for (int oo = 0; oo < 4; ++oo) {
      int f = (Ob + oo) * 16 + l16;
      int kf = (f ^ (f >> 3)) & 15;
      float4 lg4 = *(const float4*)&lgT[f * TK + tl];
      float4 lb4 = *(const float4*)&lbT[f * TK + tl];
#pragma unroll
      for (int r = 0; r < 4; ++r) {
        int t = tb + r;
        float hv = (acc[tt][oo][r] - mu) * rs * (&lg4.x)[r] + (&lb4.x)[r];
        HT[f * 128 + ((((t >> 3) ^ kf) << 3) | (t & 7))] = f2bf(hv);
      }
    }
  }
  __syncthreads();

  // ---- TM1: U = blkdiag_tril(L1) @ H ----
  f32x4 u[4][4];
#pragma unroll
  for (int tt = 0; tt < 4; ++tt)
#pragma unroll
    for (int oo = 0; oo < 4; ++oo) u[tt][oo] = (f32x4){0.f, 0.f, 0.f, 0.f};
#pragma unroll
  for (int ks = 0; ks < 4; ++ks) {
    short8 a[4]; bool act[4]; bool any = false;
#pragma unroll
    for (int tt = 0; tt < 4; ++tt) {
      int tile = Tb + tt, g = tile >> GSH;
      act[tt] = (ks * 32 <= tile * 16 + 15) && (ks * 32 + 31 >= (g << LOG2TK));
      if (act[tt]) { a[tt] = *(const short8*)&L1blk[(tile * 16 + l16) * 128 + ks * 32 + quad * 8]; any = true; }
    }
    if (!any) continue;
#pragma unroll
    for (int oo = 0; oo < 4; ++oo) {
      int f = (Ob + oo) * 16 + l16;
      int kf = (f ^ (f >> 3)) & 15;
      short8 b = *(const short8*)&HT[f * 128 + (((ks * 4 + quad) ^ kf) << 3)];
#pragma unroll
      for (int tt = 0; tt < 4; ++tt)
        if (act[tt]) u[tt][oo] = __builtin_amdgcn_mfma_f32_16x16x32_bf16(a[tt], b, u[tt][oo], 0, 0, 0);
    }
  }
  __syncthreads();

  // ---- UT = bf16(hswish(U)) ----
#pragma unroll
  for (int tt = 0; tt < 4; ++tt) {
    int tile = Tb + tt;
    int tb = tile * 16 + quad * 4;
#pragma unroll
    for (int oo = 0; oo < 4; ++oo) {
      int f = (Ob + oo) * 16 + l16;
      int kf = (f ^ (f >> 3)) & 15;
#pragma unroll
      for (int r = 0; r < 4; ++r) {
        int t = tb + r;
        HT[f * 128 + ((((t >> 3) ^ kf) << 3) | (t & 7))] = f2bf(hswish(u[tt][oo][r]));
      }
    }
  }
  __syncthreads();

  // ---- TM2: v = blkdiag_tril(L2) @ U ----
#pragma unroll
  for (int tt = 0; tt < 4; ++tt)
#pragma unroll
    for (int oo = 0; oo < 4; ++oo) u[tt][oo] = (f32x4){0.f, 0.f, 0.f, 0.f};
#pragma unroll
  for (int ks = 0; ks < 4; ++ks) {
    short8 a[4]; bool act[4]; bool any = false;
#pragma unroll
    for (int tt = 0; tt < 4; ++tt) {
      int tile = Tb + tt, g = tile >> GSH;
      act[tt] = (ks * 32 <= tile * 16 + 15) && (ks * 32 + 31 >= (g << LOG2TK));
      if (act[tt]) { a[tt] = *(const short8*)&L2blk[(tile * 16 + l16) * 128 + ks * 32 + quad * 8]; any = true; }
    }
    if (!any) continue;
#pragma unroll
    for (int oo = 0; oo < 4; ++oo) {
      int f = (Ob + oo) * 16 + l16;
      int kf = (f ^ (f >> 3)) & 15;
      short8 b = *(const short8*)&HT[f * 128 + (((ks * 4 + quad) ^ kf) << 3)];
#pragma unroll
      for (int tt = 0; tt < 4; ++tt)
        if (act[tt]) u[tt][oo] = __builtin_amdgcn_mfma_f32_16x16x32_bf16(a[tt], b, u[tt][oo], 0, 0, 0);
    }
  }

  // ---- fc contribution of v ----
#pragma unroll
  for (int tt = 0; tt < 4; ++tt)
#pragma unroll
    for (int r = 0; r < 4; ++r) {
      float v = 0.f;
#pragma unroll
      for (int oo = 0; oo < 4; ++oo) v += u[tt][oo][r] * scr[(Ob + oo) * 16 + l16];
      v += __shfl_xor(v, 1); v += __shfl_xor(v, 2);
      v += __shfl_xor(v, 4); v += __shfl_xor(v, 8);
      if (l16 == 0) atomicAdd(&part[(Tb + tt) * 16 + quad * 4 + r], v);
    }
  __syncthreads();

  // ---- output h + global LN stats contribution ----
  if (tid < 128) {
    float val = part[tid] + fc_b[0];
    int g = tid >> LOG2TK, tl = tid & TKM;
    h_out[(size_t)(n0 + g) * 224 + OFF + tl] = val;
    float s = val, q = val * val;
#pragma unroll
    for (int m = 32; m >= 1; m >>= 1) { s += __shfl_xor(s, m); q += __shfl_xor(q, m); }
    if (lane == 0) {
      int slot = (int)(blockIdx.x & 31);
      atomicAdd(&stats[2 * slot], s);
      atomicAdd(&stats[2 * slot + 1], q);
    }
  }
}

// ---------------------------------------------------------------------------
// Stage 2
// ---------------------------------------------------------------------------
__global__ void mix1_kernel(const float* __restrict__ h,
                            const float* __restrict__ sm_lg,
                            const float* __restrict__ sm_lb,
                            const float* __restrict__ m1t,
                            const float* __restrict__ stats,
                            float* __restrict__ A) {
  const int m = blockIdx.x;        // 0..223
  const int seg = blockIdx.y;      // 0..3
  const int r = threadIdx.x & 63, c = threadIdx.x >> 6;
  float S = 0.f, Q = 0.f;
#pragma unroll
  for (int s = 0; s < 32; ++s) { S += stats[2 * s]; Q += stats[2 * s + 1]; }
  const float inv = 1.f / 917504.f;
  float mu = S * inv;
  float rsig = rsqrtf(Q * inv - mu * mu + 1e-5f);
  float acc = 0.f;
  const int n0 = seg * 1024 + c * 256;
  for (int i = 0; i < 256; ++i) {
    int n = n0 + i;
    float hn = (h[n * 224 + m] - mu) * rsig * sm_lg[n * 224 + m] + sm_lb[n * 224 + m];
    acc += m1t[n * 64 + r] * hn;
  }
  __shared__ float red[256];
  red[threadIdx.x] = acc;
  __syncthreads();
  if (threadIdx.x < 64)
    atomicAdd(&A[threadIdx.x * 224 + m],
              red[threadIdx.x] + red[64 + threadIdx.x] + red[128 + threadIdx.x] + red[192 + threadIdx.x]);
}

__global__ void mix2_kernel(const float* __restrict__ A,
                            const float* __restrict__ sm_fc_w,
                            float* __restrict__ cvec) {
  int r = threadIdx.x & 63, ch = threadIdx.x >> 6;
  float acc = 0.f;
  for (int j = ch; j < 224; j += 4)
    acc += hswish(A[r * 224 + j]) * sm_fc_w[224 + j];
  __shared__ float red[256];
  red[threadIdx.x] = acc;
  __syncthreads();
  if (threadIdx.x < 64)
    cvec[threadIdx.x] = red[threadIdx.x] + red[64 + threadIdx.x] + red[128 + threadIdx.x] + red[192 + threadIdx.x];
}

__global__ void out_kernel(const float* __restrict__ h,
                           const float* __restrict__ M2,
                           const float* __restrict__ cvec,
                           const float* __restrict__ sm_fc_w,
                           const float* __restrict__ sm_fc_b,
                           float* __restrict__ out) {
  int wave = threadIdx.x >> 6, lane = threadIdx.x & 63;
  int n = blockIdx.x * 4 + wave;
  float acc = M2[n * 64 + lane] * cvec[lane];
  for (int j = lane; j < 224; j += 64)
    acc += h[n * 224 + j] * (sm_fc_w[j] + sm_fc_w[224 + j]);
#pragma unroll
  for (int m = 32; m >= 1; m >>= 1) acc += __shfl_xor(acc, m);
  if (lane == 0) out[n] = acc + sm_fc_b[0];
}

// ---------------------------------------------------------------------------
extern "C" void kernel_launch(void* const* d_in, const int* in_sizes, int n_in,
                              void* d_out, int out_size, void* d_ws, size_t ws_size,
                              hipStream_t stream) {
  const float* x      = (const float*)d_in[0];
  const float* cw0    = (const float*)d_in[1];
  const float* cb0    = (const float*)d_in[2];
  const float* lg0    = (const float*)d_in[3];
  const float* lb0    = (const float*)d_in[4];
  const float* L1_0   = (const float*)d_in[5];
  const float* L2_0   = (const float*)d_in[6];
  const float* cw1    = (const float*)d_in[7];
  const float* cb1    = (const float*)d_in[8];
  const float* lg1    = (const float*)d_in[9];
  const float* lb1    = (const float*)d_in[10];
  const float* L1_1   = (const float*)d_in[11];
  const float* L2_1   = (const float*)d_in[12];
  const float* cw2    = (const float*)d_in[13];
  const float* cb2    = (const float*)d_in[14];
  const float* lg2    = (const float*)d_in[15];
  const float* lb2    = (const float*)d_in[16];
  const float* L1_2   = (const float*)d_in[17];
  const float* L2_2   = (const float*)d_in[18];
  const float* fc_w   = (const float*)d_in[19];
  const float* fc_b   = (const float*)d_in[20];
  const float* sm_lg  = (const float*)d_in[21];
  const float* sm_lb  = (const float*)d_in[22];
  const float* M1     = (const float*)d_in[23];
  const float* M2     = (const float*)d_in[24];
  const float* sm_fc_w = (const float*)d_in[25];
  const float* sm_fc_b = (const float*)d_in[26];

  char* ws = (char*)d_ws;
  unsigned short* ws16 = (unsigned short*)(ws + WS16_OFF);
  float* m1t   = (float*)(ws + M1T_OFF);
  float* h     = (float*)(ws + H_OFF);
  float* stats = (float*)(ws + STATS_OFF);
  float* A     = (float*)(ws + A_OFF);
  float* cvec  = (float*)(ws + CVEC_OFF);
  unsigned short* xbf = (unsigned short*)(ws + XBF_OFF);
  const bool use_xbf = ws_size >= WS_NEED;

  const unsigned short* cwLT0 = ws16;
  const unsigned short* cwLT1 = ws16 + 16384;
  const unsigned short* cwLT2 = ws16 + 49152;
  const unsigned short* L1b0 = ws16 + 114688;
  const unsigned short* L2b0 = ws16 + 131072;
  const unsigned short* L1b1 = ws16 + 147456;
  const unsigned short* L2b1 = ws16 + 163840;
  const unsigned short* L1b2 = ws16 + 180224;
  const unsigned short* L2b2 = ws16 + 196608;
  const float* lgT0 = (const float*)(ws + LGT0_OFF);
  const float* lbT0 = (const float*)(ws + LBT0_OFF);
  const float* lgT1 = (const float*)(ws + LGT1_OFF);
  const float* lbT1 = (const float*)(ws + LBT1_OFF);
  const float* lgT2 = (const float*)(ws + LGT2_OFF);
  const float* lbT2 = (const float*)(ws + LBT2_OFF);

  prep_kernel<<<2080, 256, 0, stream>>>(cw0, cw1, cw2, L1_0, L2_0, L1_1, L2_1, L1_2, L2_2,
                                        M1, lg0, lb0, lg1, lb1, lg2, lb2, ws);
  // zero stats + A in one memset (contiguous region)
  hipMemsetAsync(ws + STATS_OFF, 0, 256 + 57344, stream);

  if (use_xbf) {
    xcvt_kernel<<<16384, 256, 0, stream>>>(x, xbf);
    s1_tile<0, true><<<4096, 256, 0, stream>>>(x, xbf, cb0, lgT0, lbT0, fc_w, fc_b, cwLT0, L1b0, L2b0, h, stats);
    s1_tile<1, true><<<2048, 256, 0, stream>>>(x, xbf, cb1, lgT1, lbT1, fc_w, fc_b, cwLT1, L1b1, L2b1, h, stats);
    s1_tile<2, true><<<1024, 256, 0, stream>>>(x, xbf, cb2, lgT2, lbT2, fc_w, fc_b, cwLT2, L1b2, L2b2, h, stats);
  } else {
    s1_tile<0, false><<<4096, 256, 0, stream>>>(x, xbf, cb0, lgT0, lbT0, fc_w, fc_b, cwLT0, L1b0, L2b0, h, stats);
    s1_tile<1, false><<<2048, 256, 0, stream>>>(x, xbf, cb1, lgT1, lbT1, fc_w, fc_b, cwLT1, L1b1, L2b1, h, stats);
    s1_tile<2, false><<<1024, 256, 0, stream>>>(x, xbf, cb2, lgT2, lbT2, fc_w, fc_b, cwLT2, L1b2, L2b2, h, stats);
  }

  mix1_kernel<<<dim3(224, 4), 256, 0, stream>>>(h, sm_lg, sm_lb, m1t, stats, A);
  mix2_kernel<<<1, 256, 0, stream>>>(A, sm_fc_w, cvec);
  out_kernel<<<1024, 256, 0, stream>>>(h, M2, cvec, sm_fc_w, sm_fc_b, (float*)d_out);
}